// Round 22
// baseline (65.170 us; speedup 1.0000x reference)
//
#include <hip/hip_runtime.h>
#include <hip/hip_bf16.h>
#include <stdint.h>
#include <math.h>

#define NS 2048
#define DD 64
#define HH 256

// flat output offsets (WAV, x, gW1, gb1, gW2, gb2)
#define XO_OFF  ((size_t)NS)                      // 2048
#define GW1_OFF (XO_OFF + (size_t)NS * DD)        // 133120
#define GB1_OFF (GW1_OFF + (size_t)NS * HH * DD)  // 33687552
#define GW2_OFF (GB1_OFF + (size_t)NS * HH)       // 34211840
#define GB2_OFF (GW2_OFF + (size_t)NS * 2 * HH)   // 35260416

struct SubKeys { uint32_t a[DD]; uint32_t b[DD]; };

// JAX/Random123 threefry2x32, 20 rounds.
__host__ __device__ static inline void tf2x32(uint32_t k0, uint32_t k1,
                                              uint32_t x0, uint32_t x1,
                                              uint32_t* o0, uint32_t* o1) {
  uint32_t ks0 = k0, ks1 = k1, ks2 = k0 ^ k1 ^ 0x1BD11BDAu;
  x0 += ks0; x1 += ks1;
#define TFROT(r) { x0 += x1; x1 = (x1 << (r)) | (x1 >> (32 - (r))); x1 ^= x0; }
  TFROT(13) TFROT(15) TFROT(26) TFROT(6)  x0 += ks1; x1 += ks2 + 1u;
  TFROT(17) TFROT(29) TFROT(16) TFROT(24) x0 += ks2; x1 += ks0 + 2u;
  TFROT(13) TFROT(15) TFROT(26) TFROT(6)  x0 += ks0; x1 += ks1 + 3u;
  TFROT(17) TFROT(29) TFROT(16) TFROT(24) x0 += ks1; x1 += ks2 + 4u;
  TFROT(13) TFROT(15) TFROT(26) TFROT(6)  x0 += ks2; x1 += ks0 + 5u;
#undef TFROT
  *o0 = x0; *o1 = x1;
}

// rcp-based branchless tanh (~2ulp). Validated on the DECISION path (R18/R21):
// absmax stayed exactly 32.0 -> zero decision flips on this seed.
__device__ static inline float fast_tanh_g(float x) {
  float t = __builtin_amdgcn_exp2f(x * 2.88539008177792681472f);
  return 1.0f - 2.0f * __builtin_amdgcn_rcpf(t + 1.0f);
}

// 64-lane sum-reduce via DPP (VALU-speed, no LDS). Result broadcast via readlane 63.
__device__ static inline float wave_red_dpp(float x) {
#define DPPADD(ctrl) \
  x += __int_as_float(__builtin_amdgcn_update_dpp(0, __float_as_int(x), (ctrl), 0xf, 0xf, true))
  DPPADD(0x111);  // row_shr:1
  DPPADD(0x112);  // row_shr:2
  DPPADD(0x114);  // row_shr:4
  DPPADD(0x118);  // row_shr:8
  DPPADD(0x142);  // row_bcast:15
  DPPADD(0x143);  // row_bcast:31
#undef DPPADD
  return __int_as_float(__builtin_amdgcn_readlane(__float_as_int(x), 63));
}

// ---- Kernel 0: build W1T [64][256] (h-major) and W1Q [64][64][4] (lane-packed) ----
__launch_bounds__(256)
__global__ void QNADE_w1t_kernel(const float* __restrict__ W1,
                                 float* __restrict__ W1T,
                                 float* __restrict__ W1Q) {
  int idx = blockIdx.x * 256 + threadIdx.x;   // 0..16383
  int h = idx >> 6, d = idx & 63;
  float v = W1[idx];
  W1T[d * 256 + h] = v;                              // B-phase: coalesced per-h
  W1Q[d * 256 + (h & 63) * 4 + (h >> 6)] = v;        // A-phase: dwordx4 per lane
}

// ---- Fused kernel: one wave samples; all 4 waves then build gW1 from LDS ----
// sw = i&3: empirically best (R13/R17/R21; spread/co-sample variants 100-110us).
// Phase B: tbuf is strictly per-wave -> NO block barriers inside B (waves stream
// independently; within-wave LDS ordering guaranteed by lgkmcnt).
__launch_bounds__(256, 8)   // 8 blocks/CU (LDS-limited)
__global__ void QNADE_fused_kernel(const float* __restrict__ W1T,
                                   const float* __restrict__ W1Q,
                                   const float* __restrict__ b1,
                                   const float* __restrict__ W2,
                                   const float* __restrict__ b2,
                                   float* __restrict__ out,
                                   SubKeys sk) {
  __shared__ float xrL[DD];           // spins
  __shared__ float dzL[2 * DD];       // per-step dz2 scalars
  __shared__ float gbL[HH];           // gb1 per hidden unit
  __shared__ float tbuf[4][16][66];   // per-wave transpose buffer (wave-private!)

  const int i    = blockIdx.x;        // sample
  const int tid  = threadIdx.x;
  const int lane = tid & 63;
  const int wv   = tid >> 6;
  const int sw   = i & 3;

  // Hoisted loads used by the gW1 phase (all waves; hides under sampling phase).
  const float w20h = W2[tid];
  const float w21h = W2[HH + tid];
  const float b1h  = b1[tid];

  if (wv == sw) {
    // ---------------- Phase A: sampling (one wave), 4 hidden units/lane ----------
    uint32_t o0, o1;
    tf2x32(sk.a[lane], sk.b[lane], 0u, (uint32_t)i, &o0, &o1);
    const float u_reg = __uint_as_float(0x3f800000u | ((o0 ^ o1) >> 9)) - 1.0f;

    float z1[4], w20f[4], w21f[4];
    float gw20[4] = {0,0,0,0}, gw21[4] = {0,0,0,0}, gb1a[4] = {0,0,0,0};
    #pragma unroll
    for (int k = 0; k < 4; ++k) {
      int h = lane + 64 * k;
      z1[k]   = b1[h];
      w20f[k] = W2[h];
      w21f[k] = W2[HH + h];
    }
    const float b20 = b2[0], b21 = b2[1];
    float wav = 1.0f, gb20 = 0.0f, gb21 = 0.0f;
    unsigned long long smask = 0ull;

    #pragma unroll 2
    for (int d = 0; d < DD; ++d) {
      const float4 w4 = *(const float4*)&W1Q[d * 256 + lane * 4];  // 1 dwordx4

      float hf[4]; float p0 = 0.0f, p1 = 0.0f;
      #pragma unroll
      for (int k = 0; k < 4; ++k) {
        hf[k] = fast_tanh_g(z1[k]);        // rcp-tanh: validated, 0 flips
        p0 = fmaf(hf[k], w20f[k], p0);
        p1 = fmaf(hf[k], w21f[k], p1);
      }
      float s0 = wave_red_dpp(p0) + b20;
      float s1 = wave_red_dpp(p1) + b21;

      // decision path: sqrt, exact IEEE div, square, clip, compare (np-faithful)
      float nrmf = sqrtf(s0 * s0 + s1 * s1);
      float psip = s0 / nrmf;
      float p    = fminf(psip * psip, 1.0f);
      unsigned long long bal = __ballot(u_reg < p);
      bool  bit  = (bal >> d) & 1ull;
      float spinf = bit ? 1.0f : -1.0f;
      if (bit) smask |= (1ull << d);

      // backward-local: gradient-only -> rcp-based (~1ulp), off decision path
      float rn   = __builtin_amdgcn_rcpf(nrmf);
      float psin = s1 * rn;
      float self = bit ? psip : psin;
      wav *= self;
      float gf   = __builtin_amdgcn_rcpf(self);
      float dz20 = ((bit ? gf : 0.0f) - psip) * rn;
      float dz21 = ((bit ? 0.0f : gf) - psin) * rn;
      gb20 += dz20; gb21 += dz21;

      #pragma unroll
      for (int k = 0; k < 4; ++k) {
        gw20[k] = fmaf(dz20, hf[k], gw20[k]);
        gw21[k] = fmaf(dz21, hf[k], gw21[k]);
        float dz1k = (dz20 * w20f[k] + dz21 * w21f[k]) * (1.0f - hf[k] * hf[k]);
        gb1a[k] += dz1k;
        float wk = (k == 0) ? w4.x : (k == 1) ? w4.y : (k == 2) ? w4.z : w4.w;
        z1[k] = fmaf(spinf, wk, z1[k]);
      }

      if (lane == 0) { xrL[d] = spinf; dzL[d] = dz20; dzL[DD + d] = dz21; }
    }

    // epilogue (sampling wave): publish to LDS + global small outputs
    out[XO_OFF + (size_t)i * DD + lane] = ((smask >> lane) & 1ull) ? 1.0f : -1.0f;
    #pragma unroll
    for (int k = 0; k < 4; ++k) {
      int h = lane + 64 * k;
      gbL[h] = gb1a[k];
      out[GW2_OFF + (size_t)i * 2 * HH + h]      = gw20[k];
      out[GW2_OFF + (size_t)i * 2 * HH + HH + h] = gw21[k];
      out[GB1_OFF + (size_t)i * HH + h]          = gb1a[k];
    }
    if (lane == 0) {
      out[i] = wav;
      out[GB2_OFF + (size_t)i * 2 + 0] = gb20;
      out[GB2_OFF + (size_t)i * 2 + 1] = gb21;
    }
  }
  __syncthreads();   // xrL, dzL, gbL visible to all waves (read-only afterwards)

  // -------- Phase B: gW1 via f32 replay; waves fully independent (no barriers) -----
  const size_t gw1base = GW1_OFF + (size_t)i * (HH * DD);
  const float gb1f = gbL[tid];
  float z1f = b1h;
  float pref = 0.0f;
  const int q = lane & 3, rr = lane >> 2;

  #pragma unroll
  for (int c = 0; c < 4; ++c) {
    #pragma unroll
    for (int r = 0; r < 16; ++r) {
      const int j = 16 * c + r;
      float hf  = fast_tanh_g(z1f);     // gradient-only: rcp-based
      float dz1 = (dzL[j] * w20h + dzL[DD + j] * w21h) * (1.0f - hf * hf);
      pref += dz1;
      float xv = xrL[j];
      tbuf[wv][r][lane] = xv * (gb1f - pref);      // suffix exclusive of j
      z1f = fmaf(xv, W1T[j * 256 + tid], z1f);     // coalesced
    }
    // per-wave RAW on tbuf[wv]: within-wave lgkmcnt ordering, no barrier needed
    #pragma unroll
    for (int p2 = 0; p2 < 4; ++p2) {
      const int hp = 16 * p2 + rr;
      float4 v;
      v.x = tbuf[wv][4 * q + 0][hp];
      v.y = tbuf[wv][4 * q + 1][hp];
      v.z = tbuf[wv][4 * q + 2][hp];
      v.w = tbuf[wv][4 * q + 3][hp];
      *(float4*)&out[gw1base + (size_t)(64 * wv + hp) * DD + 16 * c + 4 * q] = v;
    }
    // per-wave WAR on tbuf[wv]: same within-wave ordering, no barrier needed
  }
}

extern "C" void kernel_launch(void* const* d_in, const int* in_sizes, int n_in,
                              void* d_out, int out_size, void* d_ws, size_t ws_size,
                              hipStream_t stream) {
  (void)in_sizes; (void)n_in; (void)out_size; (void)ws_size;
  const float* W1 = (const float*)d_in[0];
  const float* b1 = (const float*)d_in[1];
  const float* W2 = (const float*)d_in[2];
  const float* b2 = (const float*)d_in[3];
  float* out = (float*)d_out;
  float* W1T = (float*)d_ws;            // 64 KB
  float* W1Q = (float*)d_ws + HH * DD;  // 64 KB

  // Host-side JAX key chain, PARTITIONABLE threefry split:
  // key(1)=(0,1); child i = threefry2x32(key,(0,i)); key=child0, sub=child1.
  SubKeys sk;
  uint32_t k0 = 0u, k1 = 1u;
  for (int d = 0; d < DD; ++d) {
    uint32_t n0, n1, s0, s1;
    tf2x32(k0, k1, 0u, 0u, &n0, &n1);
    tf2x32(k0, k1, 0u, 1u, &s0, &s1);
    sk.a[d] = s0; sk.b[d] = s1;
    k0 = n0; k1 = n1;
  }

  QNADE_w1t_kernel<<<dim3(64), dim3(256), 0, stream>>>(W1, W1T, W1Q);
  QNADE_fused_kernel<<<dim3(NS), dim3(256), 0, stream>>>(W1T, W1Q, b1, W2, b2, out, sk);
}

// Round 23
// 59.225 us; speedup vs baseline: 1.1004x; 1.1004x over previous
//
#include <hip/hip_runtime.h>
#include <hip/hip_bf16.h>
#include <stdint.h>
#include <math.h>

#define NS 2048
#define DD 64
#define HH 256

// flat output offsets (WAV, x, gW1, gb1, gW2, gb2)
#define XO_OFF  ((size_t)NS)                      // 2048
#define GW1_OFF (XO_OFF + (size_t)NS * DD)        // 133120
#define GB1_OFF (GW1_OFF + (size_t)NS * HH * DD)  // 33687552
#define GW2_OFF (GB1_OFF + (size_t)NS * HH)       // 34211840
#define GB2_OFF (GW2_OFF + (size_t)NS * 2 * HH)   // 35260416

struct SubKeys { uint32_t a[DD]; uint32_t b[DD]; };

// JAX/Random123 threefry2x32, 20 rounds.
__host__ __device__ static inline void tf2x32(uint32_t k0, uint32_t k1,
                                              uint32_t x0, uint32_t x1,
                                              uint32_t* o0, uint32_t* o1) {
  uint32_t ks0 = k0, ks1 = k1, ks2 = k0 ^ k1 ^ 0x1BD11BDAu;
  x0 += ks0; x1 += ks1;
#define TFROT(r) { x0 += x1; x1 = (x1 << (r)) | (x1 >> (32 - (r))); x1 ^= x0; }
  TFROT(13) TFROT(15) TFROT(26) TFROT(6)  x0 += ks1; x1 += ks2 + 1u;
  TFROT(17) TFROT(29) TFROT(16) TFROT(24) x0 += ks2; x1 += ks0 + 2u;
  TFROT(13) TFROT(15) TFROT(26) TFROT(6)  x0 += ks0; x1 += ks1 + 3u;
  TFROT(17) TFROT(29) TFROT(16) TFROT(24) x0 += ks1; x1 += ks2 + 4u;
  TFROT(13) TFROT(15) TFROT(26) TFROT(6)  x0 += ks2; x1 += ks0 + 5u;
#undef TFROT
  *o0 = x0; *o1 = x1;
}

// rcp-based branchless tanh (~2ulp). Validated on the DECISION path (R18/R21):
// absmax stayed exactly 32.0 -> zero decision flips on this seed.
__device__ static inline float fast_tanh_g(float x) {
  float t = __builtin_amdgcn_exp2f(x * 2.88539008177792681472f);
  return 1.0f - 2.0f * __builtin_amdgcn_rcpf(t + 1.0f);
}

// 64-lane sum-reduce via DPP (VALU-speed, no LDS). Result broadcast via readlane 63.
__device__ static inline float wave_red_dpp(float x) {
#define DPPADD(ctrl) \
  x += __int_as_float(__builtin_amdgcn_update_dpp(0, __float_as_int(x), (ctrl), 0xf, 0xf, true))
  DPPADD(0x111);  // row_shr:1
  DPPADD(0x112);  // row_shr:2
  DPPADD(0x114);  // row_shr:4
  DPPADD(0x118);  // row_shr:8
  DPPADD(0x142);  // row_bcast:15
  DPPADD(0x143);  // row_bcast:31
#undef DPPADD
  return __int_as_float(__builtin_amdgcn_readlane(__float_as_int(x), 63));
}

// ---- Kernel 0: build W1T [64][256] (h-major) and W1Q [64][64][4] (lane-packed) ----
__launch_bounds__(256)
__global__ void QNADE_w1t_kernel(const float* __restrict__ W1,
                                 float* __restrict__ W1T,
                                 float* __restrict__ W1Q) {
  int idx = blockIdx.x * 256 + threadIdx.x;   // 0..16383
  int h = idx >> 6, d = idx & 63;
  float v = W1[idx];
  W1T[d * 256 + h] = v;                              // B-phase: coalesced per-h
  W1Q[d * 256 + (h & 63) * 4 + (h >> 6)] = v;        // A-phase: dwordx4 per lane
}

// ---- Fused kernel: one wave samples; all 4 waves then build gW1 from LDS ----
// sw = i&3: empirically best. Decision via u*ss < s0^2 (sqrt/div-free; the clip
// at 1 never binds since s0^2 <= ss and u < 1).
__launch_bounds__(256, 8)   // 8 blocks/CU (LDS-limited)
__global__ void QNADE_fused_kernel(const float* __restrict__ W1T,
                                   const float* __restrict__ W1Q,
                                   const float* __restrict__ b1,
                                   const float* __restrict__ W2,
                                   const float* __restrict__ b2,
                                   float* __restrict__ out,
                                   SubKeys sk) {
  __shared__ float xrL[DD];           // spins
  __shared__ float dzL[2 * DD];       // per-step dz2 scalars
  __shared__ float gbL[HH];           // gb1 per hidden unit
  __shared__ float tbuf[4][16][66];   // per-wave transpose buffer (wave-private)

  const int i    = blockIdx.x;        // sample
  const int tid  = threadIdx.x;
  const int lane = tid & 63;
  const int wv   = tid >> 6;
  const int sw   = i & 3;

  // Hoisted loads used by the gW1 phase (all waves; hides under sampling phase).
  const float w20h = W2[tid];
  const float w21h = W2[HH + tid];
  const float b1h  = b1[tid];

  if (wv == sw) {
    // ---------------- Phase A: sampling (one wave), 4 hidden units/lane ----------
    uint32_t o0, o1;
    tf2x32(sk.a[lane], sk.b[lane], 0u, (uint32_t)i, &o0, &o1);
    const float u_reg = __uint_as_float(0x3f800000u | ((o0 ^ o1) >> 9)) - 1.0f;

    float z1[4], w20f[4], w21f[4];
    float gw20[4] = {0,0,0,0}, gw21[4] = {0,0,0,0}, gb1a[4] = {0,0,0,0};
    #pragma unroll
    for (int k = 0; k < 4; ++k) {
      int h = lane + 64 * k;
      z1[k]   = b1[h];
      w20f[k] = W2[h];
      w21f[k] = W2[HH + h];
    }
    const float b20 = b2[0], b21 = b2[1];
    float wav = 1.0f, gb20 = 0.0f, gb21 = 0.0f;
    unsigned long long smask = 0ull;

    #pragma unroll 2
    for (int d = 0; d < DD; ++d) {
      const float4 w4 = *(const float4*)&W1Q[d * 256 + lane * 4];  // 1 dwordx4

      float hf[4]; float p0 = 0.0f, p1 = 0.0f;
      #pragma unroll
      for (int k = 0; k < 4; ++k) {
        hf[k] = fast_tanh_g(z1[k]);        // rcp-tanh: validated, 0 flips
        p0 = fmaf(hf[k], w20f[k], p0);
        p1 = fmaf(hf[k], w21f[k], p1);
      }
      float s0 = wave_red_dpp(p0) + b20;
      float s1 = wave_red_dpp(p1) + b21;

      // decision: u < s0^2/(s0^2+s1^2)  <=>  u*ss < s0^2  (sqrt/div-free)
      float ss = fmaf(s0, s0, s1 * s1);
      unsigned long long bal = __ballot(u_reg * ss < s0 * s0);
      bool  bit  = (bal >> d) & 1ull;
      float spinf = bit ? 1.0f : -1.0f;
      if (bit) smask |= (1ull << d);

      // gradient scalars: rsq-based (~1ulp), gradient-only
      float rn   = __builtin_amdgcn_rsqf(ss);
      float psip = s0 * rn;
      float psin = s1 * rn;
      float self = bit ? psip : psin;
      wav *= self;
      float gf   = __builtin_amdgcn_rcpf(self);
      float dz20 = ((bit ? gf : 0.0f) - psip) * rn;
      float dz21 = ((bit ? 0.0f : gf) - psin) * rn;
      gb20 += dz20; gb21 += dz21;

      #pragma unroll
      for (int k = 0; k < 4; ++k) {
        gw20[k] = fmaf(dz20, hf[k], gw20[k]);
        gw21[k] = fmaf(dz21, hf[k], gw21[k]);
        float dz1k = (dz20 * w20f[k] + dz21 * w21f[k]) * (1.0f - hf[k] * hf[k]);
        gb1a[k] += dz1k;
        float wk = (k == 0) ? w4.x : (k == 1) ? w4.y : (k == 2) ? w4.z : w4.w;
        z1[k] = fmaf(spinf, wk, z1[k]);
      }

      if (lane == 0) { xrL[d] = spinf; dzL[d] = dz20; dzL[DD + d] = dz21; }
    }

    // epilogue (sampling wave): publish to LDS + global small outputs
    out[XO_OFF + (size_t)i * DD + lane] = ((smask >> lane) & 1ull) ? 1.0f : -1.0f;
    #pragma unroll
    for (int k = 0; k < 4; ++k) {
      int h = lane + 64 * k;
      gbL[h] = gb1a[k];
      out[GW2_OFF + (size_t)i * 2 * HH + h]      = gw20[k];
      out[GW2_OFF + (size_t)i * 2 * HH + HH + h] = gw21[k];
      out[GB1_OFF + (size_t)i * HH + h]          = gb1a[k];
    }
    if (lane == 0) {
      out[i] = wav;
      out[GB2_OFF + (size_t)i * 2 + 0] = gb20;
      out[GB2_OFF + (size_t)i * 2 + 1] = gb21;
    }
  }
  __syncthreads();   // xrL, dzL, gbL visible to all waves (read-only afterwards)

  // -------- Phase B: gW1 via f32 replay; waves fully independent (no barriers) -----
  const size_t gw1base = GW1_OFF + (size_t)i * (HH * DD);
  const float gb1f = gbL[tid];
  float z1f = b1h;
  float pref = 0.0f;
  const int q = lane & 3, rr = lane >> 2;

  #pragma unroll
  for (int c = 0; c < 4; ++c) {
    #pragma unroll
    for (int r = 0; r < 16; ++r) {
      const int j = 16 * c + r;
      float hf  = fast_tanh_g(z1f);     // gradient-only: rcp-based
      float dz1 = (dzL[j] * w20h + dzL[DD + j] * w21h) * (1.0f - hf * hf);
      pref += dz1;
      float xv = xrL[j];
      tbuf[wv][r][lane] = xv * (gb1f - pref);      // suffix exclusive of j
      z1f = fmaf(xv, W1T[j * 256 + tid], z1f);     // coalesced
    }
    // per-wave RAW/WAR on tbuf[wv]: within-wave lgkmcnt ordering, no barriers
    #pragma unroll
    for (int p2 = 0; p2 < 4; ++p2) {
      const int hp = 16 * p2 + rr;
      float4 v;
      v.x = tbuf[wv][4 * q + 0][hp];
      v.y = tbuf[wv][4 * q + 1][hp];
      v.z = tbuf[wv][4 * q + 2][hp];
      v.w = tbuf[wv][4 * q + 3][hp];
      *(float4*)&out[gw1base + (size_t)(64 * wv + hp) * DD + 16 * c + 4 * q] = v;
    }
  }
}

extern "C" void kernel_launch(void* const* d_in, const int* in_sizes, int n_in,
                              void* d_out, int out_size, void* d_ws, size_t ws_size,
                              hipStream_t stream) {
  (void)in_sizes; (void)n_in; (void)out_size; (void)ws_size;
  const float* W1 = (const float*)d_in[0];
  const float* b1 = (const float*)d_in[1];
  const float* W2 = (const float*)d_in[2];
  const float* b2 = (const float*)d_in[3];
  float* out = (float*)d_out;
  float* W1T = (float*)d_ws;            // 64 KB
  float* W1Q = (float*)d_ws + HH * DD;  // 64 KB

  // Host-side JAX key chain, PARTITIONABLE threefry split:
  // key(1)=(0,1); child i = threefry2x32(key,(0,i)); key=child0, sub=child1.
  SubKeys sk;
  uint32_t k0 = 0u, k1 = 1u;
  for (int d = 0; d < DD; ++d) {
    uint32_t n0, n1, s0, s1;
    tf2x32(k0, k1, 0u, 0u, &n0, &n1);
    tf2x32(k0, k1, 0u, 1u, &s0, &s1);
    sk.a[d] = s0; sk.b[d] = s1;
    k0 = n0; k1 = n1;
  }

  QNADE_w1t_kernel<<<dim3(64), dim3(256), 0, stream>>>(W1, W1T, W1Q);
  QNADE_fused_kernel<<<dim3(NS), dim3(256), 0, stream>>>(W1T, W1Q, b1, W2, b2, out, sk);
}